// Round 1
// baseline (1014.910 us; speedup 1.0000x reference)
//
#include <hip/hip_runtime.h>
#include <math.h>

#define DIM 128
#define BATCH 1048576
#define WT_STRIDE 136   // bf16 elements per row of W^T: 128 + 8 pad (keeps 16B align, breaks bank aliasing)

typedef float f32x4 __attribute__((ext_vector_type(4)));
typedef short bf16x8 __attribute__((ext_vector_type(8)));

// fp32 -> bf16 round-to-nearest-even (bit trick; no NaN inputs here)
__device__ __forceinline__ unsigned short f2bf(float f) {
    unsigned u = __builtin_bit_cast(unsigned, f);
    u += 0x7FFFu + ((u >> 16) & 1u);
    return (unsigned short)(u >> 16);
}

// ---------------------------------------------------------------------------
// Kernel A: build W^T (bf16, padded stride) from the Householder scan.
// Single block, 256 threads. Q register-resident: thread t holds
// Q[r][c0..c0+63], r = t&127, c0 = (t>>7)*64.  v columns staged in LDS
// (transposed, stride 129 -> conflict-free).
// ---------------------------------------------------------------------------
__global__ __launch_bounds__(256) void build_w_kernel(
    const float* __restrict__ vvec,     // [128][128], v_i = column i
    const float* __restrict__ scale_p,  // [1]
    const float* __restrict__ diag,     // [128]
    unsigned short* __restrict__ wt,    // [128][WT_STRIDE] bf16: wt[c][r] = W[r][c]
    float* __restrict__ logdet_out)
{
    __shared__ float vt[DIM * 129];     // vt[i*129 + j] = v_i[j]
    __shared__ float part[2 * DIM];
    __shared__ float scale_sh;

    const int t    = threadIdx.x;
    const int r    = t & 127;
    const int half = t >> 7;
    const int c0   = half * 64;

    // load + transpose v_vectors (coalesced read, conflict-free write via stride 129)
    for (int idx = t; idx < DIM * DIM; idx += 256) {
        int j = idx >> 7;      // row of vvec
        int i = idx & 127;     // col of vvec == step index
        vt[i * 129 + j] = vvec[idx];
    }

    // Q = I  (compile-time indices only -> stays in VGPRs)
    float q[64];
    #pragma unroll
    for (int j = 0; j < 64; ++j) q[j] = (c0 + j == r) ? 1.0f : 0.0f;

    __syncthreads();

    for (int i = 0; i < DIM; ++i) {
        const float* v = &vt[i * 129];

        // wave 0: scale = 1/(||v|| + eps)
        if (t < 64) {
            float a = v[t], b = v[t + 64];
            float ss = a * a + b * b;
            #pragma unroll
            for (int m = 32; m >= 1; m >>= 1) ss += __shfl_xor(ss, m, 64);
            if (t == 0) scale_sh = 1.0f / (sqrtf(ss) + 1e-8f);
        }

        // partial dot: sum_j Q[r][c0+j] * v_raw[c0+j]   (broadcast LDS reads)
        float dot = 0.0f;
        #pragma unroll
        for (int j = 0; j < 64; ++j) dot += q[j] * v[c0 + j];
        part[half * DIM + r] = dot;
        __syncthreads();

        // Q[r][c] -= 2*(Q vn)[r]*vn[c] = (2*scale^2*S[r]) * v_raw[c]
        const float sc   = scale_sh;
        const float coef = 2.0f * sc * sc * (part[r] + part[DIM + r]);
        #pragma unroll
        for (int j = 0; j < 64; ++j) q[j] -= coef * v[c0 + j];
        __syncthreads();   // protect part/scale_sh reuse next step
    }

    // W[r][c] = Q[r][c] * diag[c] * s ; store transposed bf16 (coalesced: lanes vary r)
    const float s = scale_p[0];
    #pragma unroll
    for (int j = 0; j < 64; ++j) {
        const int c = c0 + j;
        wt[c * WT_STRIDE + r] = f2bf(q[j] * diag[c] * s);
    }

    if (t == 0) {
        float ld = 0.0f;
        for (int c = 0; c < DIM; ++c) ld += logf(fabsf(diag[c] * s) + 1e-8f);
        *logdet_out = ld;
    }
}

// ---------------------------------------------------------------------------
// Kernel B: y = x @ W.  128 rows/block, 4 waves x 32 rows, W^T in LDS,
// mfma_f32_16x16x32_bf16.  Memory-bound: stream x in, y out.
// ---------------------------------------------------------------------------
__global__ __launch_bounds__(256) void gemm_kernel(
    const float* __restrict__ x,
    const unsigned short* __restrict__ wt,
    float* __restrict__ y)
{
    __shared__ unsigned short wlds[DIM * WT_STRIDE];   // 34816 B

    const int t = threadIdx.x;

    // stage W^T into LDS (16B chunks; pad bytes copied but never used as data)
    const int total4 = DIM * WT_STRIDE / 8;   // 2176
    for (int idx = t; idx < total4; idx += 256) {
        ((f32x4*)wlds)[idx] = ((const f32x4*)wt)[idx];
    }
    __syncthreads();

    const int wave = t >> 6;
    const int lane = t & 63;
    const int n15  = lane & 15;
    const int quad = lane >> 4;

    const long rowbase = (long)blockIdx.x * 128 + wave * 32;

    // load this wave's whole x tile up front: per lane 16x dwordx4 in flight
    f32x4 xa[2][8];
    #pragma unroll
    for (int rt = 0; rt < 2; ++rt) {
        const float* xrow = x + (rowbase + rt * 16 + n15) * DIM + quad * 8;
        #pragma unroll
        for (int kc = 0; kc < 4; ++kc) {
            xa[rt][kc * 2]     = *(const f32x4*)(xrow + kc * 32);
            xa[rt][kc * 2 + 1] = *(const f32x4*)(xrow + kc * 32 + 4);
        }
    }

    f32x4 acc[2][8];
    #pragma unroll
    for (int rt = 0; rt < 2; ++rt)
        #pragma unroll
        for (int ct = 0; ct < 8; ++ct)
            acc[rt][ct] = (f32x4)0.0f;

    #pragma unroll
    for (int kc = 0; kc < 4; ++kc) {
        // A fragments: A[m=n15][k = kc*32 + quad*8 + j]
        bf16x8 afrag[2];
        #pragma unroll
        for (int rt = 0; rt < 2; ++rt) {
            const f32x4 lo = xa[rt][kc * 2];
            const f32x4 hi = xa[rt][kc * 2 + 1];
            bf16x8 f;
            f[0] = (short)f2bf(lo[0]); f[1] = (short)f2bf(lo[1]);
            f[2] = (short)f2bf(lo[2]); f[3] = (short)f2bf(lo[3]);
            f[4] = (short)f2bf(hi[0]); f[5] = (short)f2bf(hi[1]);
            f[6] = (short)f2bf(hi[2]); f[7] = (short)f2bf(hi[3]);
            afrag[rt] = f;
        }
        const int koff = kc * 32 + quad * 8;
        #pragma unroll
        for (int ct = 0; ct < 8; ++ct) {
            // B fragment: B[k][n=n15] = W^T[n][k] -> 8 contiguous bf16 of W^T row
            const bf16x8 bfrag = *(const bf16x8*)&wlds[(ct * 16 + n15) * WT_STRIDE + koff];
            acc[0][ct] = __builtin_amdgcn_mfma_f32_16x16x32_bf16(afrag[0], bfrag, acc[0][ct], 0, 0, 0);
            acc[1][ct] = __builtin_amdgcn_mfma_f32_16x16x32_bf16(afrag[1], bfrag, acc[1][ct], 0, 0, 0);
        }
    }

    // epilogue: C/D layout col = lane&15, row = quad*4 + reg.
    // 16-lane groups write contiguous 64B segments.
    #pragma unroll
    for (int rt = 0; rt < 2; ++rt) {
        #pragma unroll
        for (int reg = 0; reg < 4; ++reg) {
            float* yrow = y + (rowbase + rt * 16 + quad * 4 + reg) * DIM;
            #pragma unroll
            for (int ct = 0; ct < 8; ++ct) {
                yrow[ct * 16 + n15] = acc[rt][ct][reg];
            }
        }
    }
}

extern "C" void kernel_launch(void* const* d_in, const int* in_sizes, int n_in,
                              void* d_out, int out_size, void* d_ws, size_t ws_size,
                              hipStream_t stream) {
    const float* x     = (const float*)d_in[0];
    const float* vvec  = (const float*)d_in[1];
    const float* scale = (const float*)d_in[2];
    const float* diag  = (const float*)d_in[3];

    float* y = (float*)d_out;
    float* logdet = y + (size_t)BATCH * DIM;        // outputs concatenated: y then logdet
    unsigned short* wt = (unsigned short*)d_ws;     // needs 128*136*2 = 34816 B

    build_w_kernel<<<1, 256, 0, stream>>>(vvec, scale, diag, wt, logdet);
    gemm_kernel<<<BATCH / 128, 256, 0, stream>>>(x, wt, y);
}